// Round 1
// baseline (138.621 us; speedup 1.0000x reference)
//
#include <hip/hip_runtime.h>
#include <math.h>

// Problem dims
#define BSZ_ 8
#define LEN_ 8192
#define NC_  128          // scan chunks per sequence
#define CT_  64           // chunk length

typedef __attribute__((ext_vector_type(8))) short bf16x8;
typedef __attribute__((ext_vector_type(4))) float f32x4;

// Workspace layout (float offsets).
#define OFF_PRM 0                                   // 128*16 per-p scalars
#define OFF_W1T 2048                                // bf16 [256][128]  (W1^T: [pc][h])
#define OFF_W2T (OFF_W1T + 16384)                   // bf16 [128][256]  (W2^T: [h][pc])
#define OFF_MPW (OFF_W2T + 16384)                   // float2 [65][128]: (m21,m22) of M^k, k-major
#define OFF_SUM (OFF_MPW + 16640)                   // f32 chunk summaries/prefixes [8][128][256][2]
#define OFF_V2  (OFF_SUM + BSZ_*NC_*256*2)          // bf16 v2 (chunk-local y) [8][8192][256]

__device__ __forceinline__ unsigned short f2bf(float f) {
    unsigned u = __builtin_bit_cast(unsigned, f);
    u += 0x7fffu + ((u >> 16) & 1u);               // round-to-nearest-even
    return (unsigned short)(u >> 16);
}

// cheap round-half-up bf16 (differs from RNE only on exact ties): 2 VALU ops
__device__ __forceinline__ unsigned short f2bf_fast(float f) {
    unsigned u = __builtin_bit_cast(unsigned, f);
    return (unsigned short)((u + 0x8000u) >> 16);
}

__device__ __forceinline__ float bf2f(unsigned short u) {
    return __builtin_bit_cast(float, (unsigned)u << 16);
}

// ---------------------------------------------------------------------------
// Setup: parallel weight conversion + per-p scalars + M-power table (k-major).
// MPW now computed fully in parallel: thread (k,p) does binary exponentiation.
// grid = 128 x 256
// ---------------------------------------------------------------------------
__global__ __launch_bounds__(256) void k_setup(const float* __restrict__ A_diag,
                                               const float* __restrict__ G_diag,
                                               const float* __restrict__ dt,
                                               const float* __restrict__ B,
                                               const float* __restrict__ C,
                                               float* __restrict__ ws)
{
    int i = blockIdx.x * 256 + threadIdx.x;        // 0..32767
    // W1T[pc][h] = c1[p] * B[p,h,c]
    {
        int pc = i >> 7, h = i & 127;
        int p = pc >> 1, cc = pc & 1;
        float dts = 1.f / (1.f + expf(-dt[p]));
        float G = fmaxf(G_diag[p], 0.f);
        float c1 = dts / (1.f + dts * G);
        ((unsigned short*)(ws + OFF_W1T))[i] = f2bf(c1 * B[p * 256 + h * 2 + cc]);
    }
    // W2T[h][pc] = +Cr / -Ci ; C layout is exactly linear in i
    {
        float v = C[i];
        ((unsigned short*)(ws + OFF_W2T))[i] = f2bf((i & 1) ? -v : v);
    }
    // M-power table, fully parallel: threads 0..8191 -> (k = 1..64, p = 0..127)
    if (i < 8192) {
        int k = (i >> 7) + 1;                      // 1..64
        int p = i & 127;
        float dtv = dt[p];
        float dts = 1.f / (1.f + expf(-dtv));
        float A   = fmaxf(A_diag[p], 0.f);
        float G   = fmaxf(G_diag[p], 0.f);
        float dt2 = fmaxf(dts * dts, 1e-6f);
        float s   = sqrtf(1.f + dts * G);
        float A_low  = (2.f + dts * G - 2.f * s) / dt2;
        float A_high = (2.f + dts * G + 2.f * s) / dt2;
        float Af = A_low + fmaxf(A - A_low, 0.f) - fmaxf(A - A_high, 0.f);
        float S   = 1.f + dts * G;
        float M11 = 1.f / S;
        float M12 = -(dts / S) * Af;
        float M21 = dts / S;
        float M22 = 1.f - (dts * dts / S) * Af;

        // R = M^k via binary exponentiation (powers of M commute)
        float r11 = 1.f, r12 = 0.f, r21 = 0.f, r22 = 1.f;
        float b11 = M11, b12 = M12, b21 = M21, b22 = M22;
        int kk = k;
#pragma unroll
        for (int it = 0; it < 7; ++it) {
            if (kk & 1) {
                float t11 = b11 * r11 + b12 * r21;
                float t12 = b11 * r12 + b12 * r22;
                float t21 = b21 * r11 + b22 * r21;
                float t22 = b21 * r12 + b22 * r22;
                r11 = t11; r12 = t12; r21 = t21; r22 = t22;
            }
            float s11 = b11 * b11 + b12 * b21;
            float s12 = b11 * b12 + b12 * b22;
            float s21 = b21 * b11 + b22 * b21;
            float s22 = b21 * b12 + b22 * b22;
            b11 = s11; b12 = s12; b21 = s21; b22 = s22;
            kk >>= 1;
        }
        float2* MPW = (float2*)(ws + OFF_MPW);
        MPW[k * 128 + p] = make_float2(r21, r22);

        float* prm = ws + OFF_PRM + p * 16;
        if (k == 1) {
            prm[0] = M11; prm[1] = M12; prm[2] = M21; prm[3] = M22; prm[4] = dts;
        }
        if (k == 64) {                              // M^64 for scan2
            prm[5] = r11; prm[6] = r12; prm[7] = r21; prm[8] = r22;
        }
    }
}

// ---------------------------------------------------------------------------
// Shared device pieces
// ---------------------------------------------------------------------------
__device__ __forceinline__ void stage_x(const float* __restrict__ X, size_t row0,
                                        int tid, unsigned short (*xs)[136])
{
    int r = tid >> 4, cl = (tid & 15) * 8;
#pragma unroll
    for (int i = 0; i < 4; ++i) {
        int rr = r + i * 16;
        const float* src = X + (row0 + rr) * 128 + cl;
        float4 v0 = *(const float4*)src;
        float4 v1 = *(const float4*)(src + 4);
        unsigned short* dst = &xs[rr][cl];
        dst[0] = f2bf_fast(v0.x); dst[1] = f2bf_fast(v0.y); dst[2] = f2bf_fast(v0.z); dst[3] = f2bf_fast(v0.w);
        dst[4] = f2bf_fast(v1.x); dst[5] = f2bf_fast(v1.y); dst[6] = f2bf_fast(v1.z); dst[7] = f2bf_fast(v1.w);
    }
}

// GEMM1 64x256x128: A = xs (LDS), B-frags straight from global W1T (L2-hot)
__device__ __forceinline__ void gemm1_acc(const unsigned short (*xs)[136],
                                          const unsigned short* __restrict__ W1T,
                                          int wv, int lane, f32x4 acc[4][4])
{
    int l15 = lane & 15, quad = lane >> 4;
    int nbase = wv * 64;
#pragma unroll
    for (int kk = 0; kk < 4; ++kk) {
        int k0 = kk * 32 + quad * 8;
        bf16x8 af[4], bg[4];
#pragma unroll
        for (int mi = 0; mi < 4; ++mi) af[mi] = *(const bf16x8*)&xs[mi * 16 + l15][k0];
#pragma unroll
        for (int nj = 0; nj < 4; ++nj)
            bg[nj] = *(const bf16x8*)(W1T + (size_t)(nbase + nj * 16 + l15) * 128 + k0);
#pragma unroll
        for (int mi = 0; mi < 4; ++mi)
#pragma unroll
            for (int nj = 0; nj < 4; ++nj)
                acc[mi][nj] = __builtin_amdgcn_mfma_f32_16x16x32_bf16(af[mi], bg[nj], acc[mi][nj], 0, 0, 0);
    }
}

// ---------------------------------------------------------------------------
// Fused 1: GEMM1 + chunk-local scan (fp32 state, zero init) in TWO 32-row
// halves through a 32-row fl buffer aliased over xs.  Scan uses the exact
// identity M21 = dts*M11, M22 = 1 + dts*M12  =>  n2 = h2 + dts*n1  (3 FMA).
// Writes v2 (=local y) bf16 to global + chunk summary.
// LDS = 32*260*4 = 33.3 KB -> 4 blk/CU.  grid = 1024 x 256
// ---------------------------------------------------------------------------
__global__ __launch_bounds__(256) void k_fuse1(const float* __restrict__ X,
                                               float* __restrict__ ws)
{
    __shared__ __align__(16) char smem[32 * 260 * 4];
    unsigned short (*xs)[136] = (unsigned short (*)[136])smem;  // alias (dead after GEMM1)
    float (*fl)[260] = (float (*)[260])smem;                    // fp32 half-tile (32 rows)

    int tid = threadIdx.x;
    int b = blockIdx.x >> 7, c = blockIdx.x & 127;
    size_t row0 = (size_t)b * LEN_ + (size_t)c * CT_;

    stage_x(X, row0, tid, xs);
    __syncthreads();

    int wv = tid >> 6, lane = tid & 63;
    int l15 = lane & 15, quad = lane >> 4, nbase = wv * 64;
    f32x4 acc[4][4] = {};
    gemm1_acc(xs, (const unsigned short*)(ws + OFF_W1T), wv, lane, acc);
    __syncthreads();            // xs fully consumed; fl may now overwrite it

    const float* prm = ws + OFF_PRM + (tid >> 1) * 16;
    float M11 = prm[0], M12 = prm[1], dts = prm[4];
    unsigned short* V2b = (unsigned short*)(ws + OFF_V2);
    float h1 = 0.f, h2 = 0.f;

#pragma unroll
    for (int half = 0; half < 2; ++half) {
        // stage rows [half*32, half*32+32) of acc into fl
#pragma unroll
        for (int mi = 0; mi < 2; ++mi)
#pragma unroll
            for (int nj = 0; nj < 4; ++nj)
#pragma unroll
                for (int r = 0; r < 4; ++r)
                    fl[mi * 16 + quad * 4 + r][nbase + nj * 16 + l15] =
                        acc[half * 2 + mi][nj][r];
        __syncthreads();
        // scan 32 rows (state carries across halves in registers)
#pragma unroll 8
        for (int t = 0; t < 32; ++t) {
            float u = fl[t][tid];
            float n1 = fmaf(M11, h1, fmaf(M12, h2, u));
            float n2 = fmaf(dts, n1, h2);          // == M21*h1 + M22*h2 + dts*u
            h1 = n1; h2 = n2;
            V2b[(row0 + half * 32 + t) * 256 + tid] = f2bf_fast(h2);
        }
        __syncthreads();        // fl reads done before next half overwrites
    }
    *(float2*)(ws + OFF_SUM + (((size_t)b * NC_ + c) * 256 + tid) * 2) = make_float2(h1, h2);
}

// ---------------------------------------------------------------------------
// Pass 2: sequential combine of chunk summaries -> exclusive prefixes.
// grid = 32 x 64
// ---------------------------------------------------------------------------
__global__ __launch_bounds__(64) void k_scan2(float* __restrict__ ws)
{
    int b = blockIdx.x >> 2, cg = blockIdx.x & 3;
    int ch = cg * 64 + threadIdx.x;
    const float* prm = ws + OFF_PRM + (ch >> 1) * 16;
    float T11 = prm[5], T12 = prm[6], T21 = prm[7], T22 = prm[8];
    float e1 = 0.f, e2 = 0.f;
    float* base = ws + OFF_SUM + (size_t)b * 65536 + ch * 2;
#pragma unroll 8
    for (int j = 0; j < NC_; ++j) {
        float2 l = *(float2*)(base + (size_t)j * 512);
        *(float2*)(base + (size_t)j * 512) = make_float2(e1, e2);
        float n1 = fmaf(T11, e1, fmaf(T12, e2, l.x));
        float n2 = fmaf(T21, e1, fmaf(T22, e2, l.y));
        e1 = n1; e2 = n2;
    }
}

// ---------------------------------------------------------------------------
// Fused 2: ys_t = v2_t + [M^{t+1} C]_2  (v2 bf16 from global, C = chunk
// prefix fp32, M-powers fp32 from table) -> ysb LDS bf16 -> GEMM2 + D.*x.
// Combine is channel-pair vectorized: thread handles channels (2q, 2q+1)
// (same p -> shared MPW entry) over 32 t's; ushort2 V2 loads, float4 prefix.
// LDS = 33.8 KB -> 4 blk/CU.  grid = 1024 x 256
// ---------------------------------------------------------------------------
__global__ __launch_bounds__(256) void k_fuse2(const float* __restrict__ X,
                                               const float* __restrict__ Dv,
                                               float* __restrict__ ws,
                                               float* __restrict__ out)
{
    __shared__ __align__(16) unsigned short ysb[64][264];

    int tid = threadIdx.x;
    int b = blockIdx.x >> 7, c = blockIdx.x & 127;
    size_t row0 = (size_t)b * LEN_ + (size_t)c * CT_;

    // ---- build ys tile: thread = (channel pair q, t-segment) ----
    {
        int q = tid & 127;                         // channels 2q, 2q+1 (same p=q)
        int tseg = tid >> 7;                       // t in [tseg*32, tseg*32+32)
        float4 Cp = *(const float4*)(ws + OFF_SUM +
                                     (((size_t)b * NC_ + c) * 256 + 2 * q) * 2);
        const float2* MPW = (const float2*)(ws + OFF_MPW);
        const unsigned short* V2b = (const unsigned short*)(ws + OFF_V2) +
                                    (row0 + tseg * 32) * 256 + 2 * q;
#pragma unroll 8
        for (int t = 0; t < 32; ++t) {
            int tt = tseg * 32 + t;
            ushort2 v2u = *(const ushort2*)(V2b + (size_t)t * 256);
            float2 m = MPW[(tt + 1) * 128 + q];    // (m21, m22) of M^{tt+1}
            float y0 = fmaf(m.x, Cp.x, fmaf(m.y, Cp.y, bf2f(v2u.x)));
            float y1 = fmaf(m.x, Cp.z, fmaf(m.y, Cp.w, bf2f(v2u.y)));
            *(ushort2*)&ysb[tt][2 * q] = make_ushort2(f2bf_fast(y0), f2bf_fast(y1));
        }
    }
    __syncthreads();

    // ---- GEMM2 64x128x256: A = ys (LDS bf16), B-frags from global W2T ----
    int wv = tid >> 6, lane = tid & 63;
    int l15 = lane & 15, quad = lane >> 4;
    int mrow = (wv & 1) * 32, ncol = (wv >> 1) * 64;
    f32x4 a2[2][4] = {};
    const unsigned short* W2T = (const unsigned short*)(ws + OFF_W2T);
#pragma unroll
    for (int kk = 0; kk < 8; ++kk) {
        int k0 = kk * 32 + quad * 8;
        bf16x8 af[2], bg[4];
#pragma unroll
        for (int mi = 0; mi < 2; ++mi) af[mi] = *(const bf16x8*)&ysb[mrow + mi * 16 + l15][k0];
#pragma unroll
        for (int nj = 0; nj < 4; ++nj)
            bg[nj] = *(const bf16x8*)(W2T + (size_t)(ncol + nj * 16 + l15) * 256 + k0);
#pragma unroll
        for (int mi = 0; mi < 2; ++mi)
#pragma unroll
            for (int nj = 0; nj < 4; ++nj)
                a2[mi][nj] = __builtin_amdgcn_mfma_f32_16x16x32_bf16(af[mi], bg[nj], a2[mi][nj], 0, 0, 0);
    }

    // ---- epilogue: out = a2 + D .* x (fp32 exact) ----
#pragma unroll
    for (int mi = 0; mi < 2; ++mi)
#pragma unroll
        for (int nj = 0; nj < 4; ++nj) {
            int col = ncol + nj * 16 + l15;
            float d = Dv[col];
#pragma unroll
            for (int r = 0; r < 4; ++r) {
                size_t gr = row0 + mrow + mi * 16 + quad * 4 + r;
                float xv = X[gr * 128 + col];
                out[gr * 128 + col] = fmaf(d, xv, a2[mi][nj][r]);
            }
        }
}

// ---------------------------------------------------------------------------
extern "C" void kernel_launch(void* const* d_in, const int* in_sizes, int n_in,
                              void* d_out, int out_size, void* d_ws, size_t ws_size,
                              hipStream_t stream) {
    const float* x      = (const float*)d_in[0];
    const float* A_diag = (const float*)d_in[1];
    const float* G_diag = (const float*)d_in[2];
    const float* dt     = (const float*)d_in[3];
    const float* B      = (const float*)d_in[4];
    const float* C      = (const float*)d_in[5];
    const float* Dv     = (const float*)d_in[6];
    float* out = (float*)d_out;
    float* ws  = (float*)d_ws;

    k_setup<<<128, 256, 0, stream>>>(A_diag, G_diag, dt, B, C, ws);
    k_fuse1<<<BSZ_ * NC_, 256, 0, stream>>>(x, ws);
    k_scan2<<<32, 64, 0, stream>>>(ws);
    k_fuse2<<<BSZ_ * NC_, 256, 0, stream>>>(x, Dv, ws, out);
}